// Round 2
// baseline (25.712 us; speedup 1.0000x reference)
//
#include <hip/hip_runtime.h>
#include <stdint.h>

enum { B_ = 32, K_ = 16, N_ = 256 };

// ws layout (all built fresh every launch):
//   [0x000000, 0x100000)  PTX  : uint4 ((k*64+jb)*64+w), comp r = j=4jb+r, byte i = n=4w+i
//   [0x100000, 0x140000)  CTZ  : u32 ctz[(b*256+j)*8 + t] = (s[b,j] * x^t) zero-extended
//   [0x140000, 0x140080)  ACC  : int acc[32]
//   [0x140080, 0x140084)  CNT  : int counter
#define PTX_OFF  0x000000
#define CTZ_OFF  0x100000
#define ACC_OFF  0x140000
#define CNT_OFF  0x140080
#define WS2_NEED 0x140084

#define M4 0x01010101u

// ------------------------------ prep --------------------------------------
// blocks 0..63   : transpose/byteify P  (block = (k, j-quarter))
// blocks 64..95  : c-table (8192 (b,j) pairs)
// block 96       : zero acc + cnt
__global__ __launch_bounds__(256) void gf_prep(const int* __restrict__ s32,
                                               const int* __restrict__ P32,
                                               uint8_t* __restrict__ ws) {
    const int tid = threadIdx.x;
    if (blockIdx.x < 64) {
        __shared__ __align__(16) uint8_t tile[64 * 260];  // [jj][n], row pad 260
        const int kk = blockIdx.x >> 2;
        const int jq = blockIdx.x & 3;
        const int c16 = tid & 15;       // int4 chunk within the 64-j slice
        const int nb  = tid >> 4;       // n base (0..15)
        const int4* Pi4 = (const int4*)P32;
#pragma unroll 4
        for (int it = 0; it < 16; ++it) {
            const int n = nb + 16 * it;
            int4 v = Pi4[(kk * 256 + n) * 64 + jq * 16 + c16];
            const int jj = 4 * c16;
            tile[(jj + 0) * 260 + n] = (uint8_t)(v.x & 255);
            tile[(jj + 1) * 260 + n] = (uint8_t)(v.y & 255);
            tile[(jj + 2) * 260 + n] = (uint8_t)(v.z & 255);
            tile[(jj + 3) * 260 + n] = (uint8_t)(v.w & 255);
        }
        __syncthreads();
        const int w = tid & 63;
        uint4* PTX4 = (uint4*)(ws + PTX_OFF);
#pragma unroll
        for (int pb = 0; pb < 4; ++pb) {
            const int jbb = (tid >> 6) + 4 * pb;  // local 4-j group (0..15)
            uint4 o;
            o.x = *(const uint32_t*)(tile + (4 * jbb + 0) * 260 + 4 * w);
            o.y = *(const uint32_t*)(tile + (4 * jbb + 1) * 260 + 4 * w);
            o.z = *(const uint32_t*)(tile + (4 * jbb + 2) * 260 + 4 * w);
            o.w = *(const uint32_t*)(tile + (4 * jbb + 3) * 260 + 4 * w);
            PTX4[(kk * 64 + jq * 16 + jbb) * 64 + w] = o;
        }
    } else if (blockIdx.x < 96) {
        const int g = (blockIdx.x - 64) * 256 + tid;  // 0..8191
        const int b = g >> 8, j = g & 255;
        uint32_t c = (uint32_t)s32[b * 256 + j] & 255u;
        uint32_t cv[8];
#pragma unroll
        for (int t = 0; t < 8; ++t) {
            cv[t] = c;
            c = ((c << 1) & 255u) ^ (((c >> 7) & 1u) * 29u);
        }
        uint4* ctz4 = (uint4*)(ws + CTZ_OFF);
        uint4 w0 = {cv[0], cv[1], cv[2], cv[3]};
        uint4 w1 = {cv[4], cv[5], cv[6], cv[7]};
        ctz4[(b * 256 + j) * 2 + 0] = w0;
        ctz4[(b * 256 + j) * 2 + 1] = w1;
    } else {
        if (tid < 32) ((int*)(ws + ACC_OFF))[tid] = 0;
        if (tid == 32) *((int*)(ws + CNT_OFF)) = 0;
    }
}

// ------------------------------ main --------------------------------------
// grid 512 = (b,k), 512 threads (8 waves). Wave q handles j in [32q, 32q+32),
// lane w owns n-word w (n = 4w..4w+3). SWAR: res ^= ((p>>t)&0x01010101)*c_t.
#define STEP8(p, u, v)                       \
    r0 ^= (p & M4) * u.x; p >>= 1;           \
    r1 ^= (p & M4) * u.y; p >>= 1;           \
    r0 ^= (p & M4) * u.z; p >>= 1;           \
    r1 ^= (p & M4) * u.w; p >>= 1;           \
    r0 ^= (p & M4) * v.x; p >>= 1;           \
    r1 ^= (p & M4) * v.y; p >>= 1;           \
    r0 ^= (p & M4) * v.z; p >>= 1;           \
    r1 ^= (p & M4) * v.w;

__global__ __launch_bounds__(512) void gf_main2(const int* __restrict__ m32,
                                                uint8_t* __restrict__ ws,
                                                int* __restrict__ dout) {
    __shared__ __align__(16) uint32_t cpl[2048];  // [j][t] c-words for this b
    __shared__ uint32_t xch[8 * 64];
    __shared__ uint32_t wr4[8];
    __shared__ int isLast;

    const int b = blockIdx.x >> 4, k = blockIdx.x & 15;
    const int tid = threadIdx.x, q = tid >> 6, w = tid & 63;

    ((uint4*)cpl)[tid] = ((const uint4*)(ws + CTZ_OFF))[b * 512 + tid];
    __syncthreads();

    const uint4* pt = (const uint4*)(ws + PTX_OFF) + (size_t)(k * 64 + q * 8) * 64 + w;
    uint32_t r0 = 0, r1 = 0;
#pragma unroll
    for (int i = 0; i < 8; ++i) {
        const int jb = q * 8 + i;
        uint4 pv = pt[i * 64];
        const uint32_t* cj = &cpl[jb * 32];
        uint4 cA = *(const uint4*)(cj + 0);
        uint4 cB = *(const uint4*)(cj + 4);
        uint4 cC = *(const uint4*)(cj + 8);
        uint4 cD = *(const uint4*)(cj + 12);
        uint4 cE = *(const uint4*)(cj + 16);
        uint4 cF = *(const uint4*)(cj + 20);
        uint4 cG = *(const uint4*)(cj + 24);
        uint4 cH = *(const uint4*)(cj + 28);
        uint32_t px = pv.x, py = pv.y, pz = pv.z, pq = pv.w;
        STEP8(px, cA, cB)
        STEP8(py, cC, cD)
        STEP8(pz, cE, cF)
        STEP8(pq, cG, cH)
    }
    xch[q * 64 + w] = r0 ^ r1;
    __syncthreads();

    // stage 2: thread n<256 computes mul(stP[n], s[b,n]) via its own c-words
    uint32_t acc = 0;
    if (tid < 256) {
        const int nw = tid >> 2, sh = (tid & 3) * 8;
        uint32_t sp = 0;
#pragma unroll
        for (int qq = 0; qq < 8; ++qq) sp ^= xch[qq * 64 + nw];
        sp = (sp >> sh) & 255u;
        const uint32_t* cj = &cpl[tid * 8];
        uint4 cA = *(const uint4*)(cj + 0);
        uint4 cB = *(const uint4*)(cj + 4);
        acc ^= (0u - ((sp >> 0) & 1u)) & cA.x;
        acc ^= (0u - ((sp >> 1) & 1u)) & cA.y;
        acc ^= (0u - ((sp >> 2) & 1u)) & cA.z;
        acc ^= (0u - ((sp >> 3) & 1u)) & cA.w;
        acc ^= (0u - ((sp >> 4) & 1u)) & cB.x;
        acc ^= (0u - ((sp >> 5) & 1u)) & cB.y;
        acc ^= (0u - ((sp >> 6) & 1u)) & cB.z;
        acc ^= (0u - ((sp >> 7) & 1u)) & cB.w;
    }
#pragma unroll
    for (int off = 1; off < 64; off <<= 1) acc ^= __shfl_xor(acc, off, 64);
    if (w == 0) wr4[q] = acc;
    __syncthreads();

    int* accb = (int*)(ws + ACC_OFF);
    int* cnt  = (int*)(ws + CNT_OFF);
    if (tid == 0) {
        uint32_t tot = wr4[0] ^ wr4[1] ^ wr4[2] ^ wr4[3];
        atomicAdd(&accb[b], (int)tot - m32[b * 16 + k]);
        __threadfence();
        int old = atomicAdd(cnt, 1);
        isLast = (old == 511) ? 1 : 0;
    }
    __syncthreads();
    if (isLast && tid < 32) {
        int v = atomicAdd(&accb[tid], 0);  // coherent read
        dout[tid] = max(1 - v, 0);
    }
}

// ------------------------- fallback (tiny ws) ------------------------------
__device__ __forceinline__ uint32_t pack4i(int4 v) {
    return (uint32_t)(v.x & 255) | ((uint32_t)(v.y & 255) << 8) |
           ((uint32_t)(v.z & 255) << 16) | ((uint32_t)(v.w & 255) << 24);
}
__global__ void prep_zero(int* __restrict__ out) {
    if (threadIdx.x < B_) out[threadIdx.x] = 0;
}
#define LK(sw, pw)                                                  \
    v ^= tbl[(((sw) & 255u) << 8) | ((pw) & 255u)];                 \
    v ^= tbl[((sw) & 0xFF00u) | (((pw) >> 8) & 255u)];              \
    v ^= tbl[(((sw) >> 8) & 0xFF00u) | (((pw) >> 16) & 255u)];      \
    v ^= tbl[(((sw) >> 16) & 0xFF00u) | ((pw) >> 24)];
__global__ __launch_bounds__(256) void gf_main_fb(const int* __restrict__ m,
                                                  const int* __restrict__ s32,
                                                  const int* __restrict__ P32,
                                                  const int* __restrict__ t32,
                                                  int* __restrict__ out) {
    __shared__ uint8_t tbl[65536];
    __shared__ uint8_t sb[256];
    __shared__ uint32_t wred[4];
    const int b = blockIdx.x >> 4, k = blockIdx.x & 15, tid = threadIdx.x;
    for (int i = tid; i < 16384; i += 256) {
        int4 v = ((const int4*)t32)[i];
        ((uint32_t*)tbl)[i] = pack4i(v);
    }
    if (tid < 64) {
        int4 v = ((const int4*)s32)[b * 64 + tid];
        ((uint32_t*)sb)[tid] = pack4i(v);
    }
    __syncthreads();
    uint32_t v = 0;
    const uint32_t* sw32 = (const uint32_t*)sb;
    const int4* prow32 = (const int4*)(P32 + ((size_t)k * N_ + tid) * N_);
#pragma unroll 4
    for (int j0 = 0; j0 < 64; j0 += 4) {
        uint32_t p0 = pack4i(prow32[j0]), p1 = pack4i(prow32[j0 + 1]);
        uint32_t p2 = pack4i(prow32[j0 + 2]), p3 = pack4i(prow32[j0 + 3]);
        uint32_t w0 = sw32[j0], w1 = sw32[j0 + 1], w2 = sw32[j0 + 2], w3 = sw32[j0 + 3];
        LK(w0, p0) LK(w1, p1) LK(w2, p2) LK(w3, p3)
    }
    uint32_t wv = tbl[(v << 8) | (uint32_t)sb[tid]];
#pragma unroll
    for (int off = 1; off < 64; off <<= 1) wv ^= __shfl_xor(wv, off, 64);
    if ((tid & 63) == 0) wred[tid >> 6] = wv;
    __syncthreads();
    if (tid == 0) {
        uint32_t x = wred[0] ^ wred[1] ^ wred[2] ^ wred[3];
        atomicAdd(&out[b], (int)x - m[b * K_ + k]);
    }
}
__global__ void gf_finish(int* __restrict__ out) {
    if (threadIdx.x < B_) {
        int v = out[threadIdx.x];
        out[threadIdx.x] = max(1 - v, 0);
    }
}

extern "C" void kernel_launch(void* const* d_in, const int* in_sizes, int n_in,
                              void* d_out, int out_size, void* d_ws, size_t ws_size,
                              hipStream_t stream) {
    const int* m     = (const int*)d_in[0];
    const int* s     = (const int*)d_in[1];
    const int* P     = (const int*)d_in[2];
    const int* table = (const int*)d_in[3];
    int* out = (int*)d_out;

    if (ws_size >= (size_t)WS2_NEED) {
        uint8_t* ws = (uint8_t*)d_ws;
        gf_prep<<<97, 256, 0, stream>>>(s, P, ws);
        gf_main2<<<B_ * K_, 512, 0, stream>>>(m, ws, out);
    } else {
        prep_zero<<<1, 64, 0, stream>>>(out);
        gf_main_fb<<<B_ * K_, 256, 0, stream>>>(m, s, P, table, out);
        gf_finish<<<1, 64, 0, stream>>>(out);
    }
}

// Round 3
// 25.316 us; speedup vs baseline: 1.0156x; 1.0156x over previous
//
#include <hip/hip_runtime.h>
#include <stdint.h>

enum { B_ = 32, K_ = 16, N_ = 256 };

// ws layout (rebuilt every launch):
//   [0x000000, 0x100000)  PVT : uint4[(k*16+jg)*256 + n]  byte-packed P, word-transposed
//   [0x100000, 0x110000)  CVW : u32 cv[(b*8+r)*64 + w]    C-bit words
//   [0x110000, 0x120000)  CVT : u64 cvt[b*256 + n]        C bytes r-major (stage 2)
//   [0x120000, 0x120080)  ACC : int acc[32]
//   [0x120080, 0x120084)  CNT : int counter
#define PVT_OFF  0x000000
#define CVW_OFF  0x100000
#define CVT_OFF  0x110000
#define ACC_OFF  0x120000
#define CNT_OFF  0x120080
#define WS_NEED  0x120084

__device__ __forceinline__ uint32_t pack4i(int4 v) {
    return (uint32_t)(v.x & 255) | ((uint32_t)(v.y & 255) << 8) |
           ((uint32_t)(v.z & 255) << 16) | ((uint32_t)(v.w & 255) << 24);
}

// ------------------------------ prep --------------------------------------
// blocks 0..31 : byte-pack + word-transpose P  (block = (k, n-half))
// blocks 32..63: C tables (8192 (b,j) pairs): CVW words + CVT bytes
// block 64     : zero acc + cnt
__global__ __launch_bounds__(256) void gf_prep(const int* __restrict__ s32,
                                               const int* __restrict__ P32,
                                               uint8_t* __restrict__ ws) {
    const int tid = threadIdx.x;
    const int bid = blockIdx.x;
    if (bid < 32) {
        __shared__ uint32_t tile[128 * 65];  // [nl][jw], pad 65 (conflict-free)
        const int k = bid >> 1, nh = bid & 1;
        const int4* in = (const int4*)P32 + (size_t)(k * 256 + nh * 128) * 64;
#pragma unroll 8
        for (int i = 0; i < 32; ++i) {
            const int idx = tid + 256 * i;          // 0..8191, fully coalesced read
            int4 v = in[idx];
            const int jw = idx & 63, nl = idx >> 6;
            tile[nl * 65 + jw] = pack4i(v);
        }
        __syncthreads();
        uint4* out = (uint4*)(ws + PVT_OFF);
#pragma unroll
        for (int it = 0; it < 8; ++it) {
            const int oid = tid + 256 * it;         // 0..2047
            const int jg = oid >> 7, nl = oid & 127;
            uint4 o;
            o.x = tile[nl * 65 + 4 * jg + 0];
            o.y = tile[nl * 65 + 4 * jg + 1];
            o.z = tile[nl * 65 + 4 * jg + 2];
            o.w = tile[nl * 65 + 4 * jg + 3];
            out[(k * 16 + jg) * 256 + nh * 128 + nl] = o;  // coalesced uint4 store
        }
    } else if (bid < 64) {
        const int g = (bid - 32) * 256 + tid;  // 0..8191
        const int b = g >> 8, j = g & 255;
        uint32_t c = (uint32_t)s32[b * 256 + j] & 255u;
        uint32_t A = 0, Bw = 0;
#pragma unroll
        for (int u = 0; u < 4; ++u) {
            A |= c << (8 * u);
            c = ((c << 1) & 255u) ^ ((c >> 7) * 29u);
        }
#pragma unroll
        for (int u = 0; u < 4; ++u) {
            Bw |= c << (8 * u);
            c = ((c << 1) & 255u) ^ ((c >> 7) * 29u);
        }
        uint8_t* cvb = ws + CVW_OFF;
        uint32_t by[8];
#pragma unroll
        for (int r = 0; r < 8; ++r) {
            uint32_t t = (A >> r) & 0x01010101u;
            uint32_t lo = (t | (t >> 7) | (t >> 14) | (t >> 21)) & 15u;
            uint32_t u2 = (Bw >> r) & 0x01010101u;
            uint32_t hi = (u2 | (u2 >> 7) | (u2 >> 14) | (u2 >> 21)) & 15u;
            by[r] = lo | (hi << 4);
            cvb[(b * 8 + r) * 256 + j] = (uint8_t)by[r];  // coalesced per-r byte rows
        }
        uint2 ct;
        ct.x = by[0] | (by[1] << 8) | (by[2] << 16) | (by[3] << 24);
        ct.y = by[4] | (by[5] << 8) | (by[6] << 16) | (by[7] << 24);
        ((uint2*)(ws + CVT_OFF))[b * 256 + j] = ct;  // coalesced 8B store
    } else {
        if (tid < 32) ((int*)(ws + ACC_OFF))[tid] = 0;
        if (tid == 32) *((int*)(ws + CNT_OFF)) = 0;
    }
}

// ------------------------------ main --------------------------------------
// grid 512 = (b,k), 512 threads. Thread (n = tid&255, h = tid>>8) computes the
// h-half (j 128h..128h+127) of all 8 parity bits of stP[b,k,n]:
//   xr[r] = XOR_w ( Pword[k,n,w] & Cword[b,r,w] ),  bit_r = parity(xr[r]).
// C-words are block-uniform -> scalar loads. Zero LDS in the hot loop.
__global__ __launch_bounds__(512) void gf_main3(const int* __restrict__ m32,
                                                uint8_t* __restrict__ ws,
                                                int* __restrict__ dout) {
    __shared__ uint32_t xch[512];
    __shared__ uint32_t wr4[4];
    __shared__ int isLast;

    const int b = blockIdx.x >> 4, k = blockIdx.x & 15;
    const int tid = threadIdx.x;
    const int n = tid & 255;
    const int h = __builtin_amdgcn_readfirstlane(tid >> 8);  // wave-uniform

    const uint4* pv4 = (const uint4*)(ws + PVT_OFF) + (size_t)(k * 16 + h * 8) * 256 + n;
    const uint32_t* __restrict__ cv = (const uint32_t*)(ws + CVW_OFF) + b * 512 + h * 32;

    uint32_t xr[8] = {0, 0, 0, 0, 0, 0, 0, 0};
#pragma unroll
    for (int g = 0; g < 8; ++g) {
        uint4 pv = pv4[g * 256];  // coalesced 16B/lane
#pragma unroll
        for (int r = 0; r < 8; ++r) {
            uint32_t a;
            a  = cv[r * 64 + g * 4 + 0] & pv.x;
            a ^= cv[r * 64 + g * 4 + 1] & pv.y;
            a ^= cv[r * 64 + g * 4 + 2] & pv.z;
            a ^= cv[r * 64 + g * 4 + 3] & pv.w;
            xr[r] ^= a;
        }
    }
    uint32_t part = 0;
#pragma unroll
    for (int r = 0; r < 8; ++r) part |= (uint32_t)(__popc(xr[r]) & 1) << r;
    xch[tid] = part;
    __syncthreads();

    // stage 2: thread n<256: stP byte -> mul(stP, s[b,n]) via CVT bytes
    uint32_t acc = 0;
    if (tid < 256) {
        uint32_t stP = xch[tid] ^ xch[tid + 256];
        uint2 ct = ((const uint2*)(ws + CVT_OFF))[b * 256 + tid];
        uint32_t prod = 0;
#pragma unroll
        for (int r = 0; r < 4; ++r)
            prod |= (uint32_t)(__popc(stP & ((ct.x >> (8 * r)) & 255u)) & 1) << r;
#pragma unroll
        for (int r = 0; r < 4; ++r)
            prod |= (uint32_t)(__popc(stP & ((ct.y >> (8 * r)) & 255u)) & 1) << (r + 4);
        acc = prod;
    }
#pragma unroll
    for (int off = 1; off < 64; off <<= 1) acc ^= __shfl_xor(acc, off, 64);
    if (tid < 256 && (tid & 63) == 0) wr4[tid >> 6] = acc;
    __syncthreads();

    int* accb = (int*)(ws + ACC_OFF);
    int* cnt  = (int*)(ws + CNT_OFF);
    if (tid == 0) {
        uint32_t tot = wr4[0] ^ wr4[1] ^ wr4[2] ^ wr4[3];
        atomicAdd(&accb[b], (int)tot - m32[b * 16 + k]);
        __threadfence();
        int old = atomicAdd(cnt, 1);
        isLast = (old == 511) ? 1 : 0;
    }
    __syncthreads();
    if (isLast && tid < 32) {
        int v = atomicAdd(&accb[tid], 0);  // coherent read
        dout[tid] = max(1 - v, 0);
    }
}

// ------------------------- fallback (tiny ws) ------------------------------
__global__ void prep_zero(int* __restrict__ out) {
    if (threadIdx.x < B_) out[threadIdx.x] = 0;
}
#define LK(sw, pw)                                                  \
    v ^= tbl[(((sw) & 255u) << 8) | ((pw) & 255u)];                 \
    v ^= tbl[((sw) & 0xFF00u) | (((pw) >> 8) & 255u)];              \
    v ^= tbl[(((sw) >> 8) & 0xFF00u) | (((pw) >> 16) & 255u)];      \
    v ^= tbl[(((sw) >> 16) & 0xFF00u) | ((pw) >> 24)];
__global__ __launch_bounds__(256) void gf_main_fb(const int* __restrict__ m,
                                                  const int* __restrict__ s32,
                                                  const int* __restrict__ P32,
                                                  const int* __restrict__ t32,
                                                  int* __restrict__ out) {
    __shared__ uint8_t tbl[65536];
    __shared__ uint8_t sb[256];
    __shared__ uint32_t wred[4];
    const int b = blockIdx.x >> 4, k = blockIdx.x & 15, tid = threadIdx.x;
    for (int i = tid; i < 16384; i += 256) {
        int4 v = ((const int4*)t32)[i];
        ((uint32_t*)tbl)[i] = pack4i(v);
    }
    if (tid < 64) {
        int4 v = ((const int4*)s32)[b * 64 + tid];
        ((uint32_t*)sb)[tid] = pack4i(v);
    }
    __syncthreads();
    uint32_t v = 0;
    const uint32_t* sw32 = (const uint32_t*)sb;
    const int4* prow32 = (const int4*)(P32 + ((size_t)k * N_ + tid) * N_);
#pragma unroll 4
    for (int j0 = 0; j0 < 64; j0 += 4) {
        uint32_t p0 = pack4i(prow32[j0]), p1 = pack4i(prow32[j0 + 1]);
        uint32_t p2 = pack4i(prow32[j0 + 2]), p3 = pack4i(prow32[j0 + 3]);
        uint32_t w0 = sw32[j0], w1 = sw32[j0 + 1], w2 = sw32[j0 + 2], w3 = sw32[j0 + 3];
        LK(w0, p0) LK(w1, p1) LK(w2, p2) LK(w3, p3)
    }
    uint32_t wv = tbl[(v << 8) | (uint32_t)sb[tid]];
#pragma unroll
    for (int off = 1; off < 64; off <<= 1) wv ^= __shfl_xor(wv, off, 64);
    if ((tid & 63) == 0) wred[tid >> 6] = wv;
    __syncthreads();
    if (tid == 0) {
        uint32_t x = wred[0] ^ wred[1] ^ wred[2] ^ wred[3];
        atomicAdd(&out[b], (int)x - m[b * K_ + k]);
    }
}
__global__ void gf_finish(int* __restrict__ out) {
    if (threadIdx.x < B_) {
        int v = out[threadIdx.x];
        out[threadIdx.x] = max(1 - v, 0);
    }
}

extern "C" void kernel_launch(void* const* d_in, const int* in_sizes, int n_in,
                              void* d_out, int out_size, void* d_ws, size_t ws_size,
                              hipStream_t stream) {
    const int* m     = (const int*)d_in[0];
    const int* s     = (const int*)d_in[1];
    const int* P     = (const int*)d_in[2];
    const int* table = (const int*)d_in[3];
    int* out = (int*)d_out;

    if (ws_size >= (size_t)WS_NEED) {
        uint8_t* ws = (uint8_t*)d_ws;
        gf_prep<<<65, 256, 0, stream>>>(s, P, ws);
        gf_main3<<<B_ * K_, 512, 0, stream>>>(m, ws, out);
    } else {
        prep_zero<<<1, 64, 0, stream>>>(out);
        gf_main_fb<<<B_ * K_, 256, 0, stream>>>(m, s, P, table, out);
        gf_finish<<<1, 64, 0, stream>>>(out);
    }
}